// Round 17
// baseline (85.374 us; speedup 1.0000x reference)
//
#include <hip/hip_runtime.h>
#include <stdint.h>

typedef unsigned short u16;
typedef __bf16 bf16x8 __attribute__((ext_vector_type(8)));
typedef float f32x4 __attribute__((ext_vector_type(4)));

#define DD 768
#define LN_EPS 1e-5f

__device__ __forceinline__ u16 f2bf(float f) {
  union { float f; unsigned u; } x; x.f = f;
  unsigned r = x.u + 0x7fffu + ((x.u >> 16) & 1u);
  return (u16)(r >> 16);
}
__device__ __forceinline__ float bf2f(u16 h) {
  union { unsigned u; float f; } x; x.u = ((unsigned)h) << 16; return x.f;
}

__device__ __forceinline__ void async16(void* ldsp, const void* g) {
  __builtin_amdgcn_global_load_lds(
      (const __attribute__((address_space(1))) void*)g,
      (__attribute__((address_space(3))) void*)ldsp,
      16, 0, 0);
}

// ---------------------------------------------------------------------------
// 128 x (NF*32) 2-phase GEMM (proven structure). 256 thr = 4 waves (2Mx2N);
// BK=64, 12 K-tiles. Swizzle: 16B chunk ^= (row&7) on pre-swizzled global
// source + ds_read addr; LDS writes linear. Zero bank conflicts (measured).
// MODE 0: bf16 raw; 1: bf16 acc+bias; 2: bf16 relu; 3: f32 relu.
// ---------------------------------------------------------------------------
template<int MODE, int NF>
__device__ __forceinline__ void gemm_body(
    const u16* __restrict__ A, const u16* __restrict__ W,
    const float* __restrict__ bias,
    void* __restrict__ Out, int bx, int by, int N, int K)
{
  const int BN = NF * 32;
  const int STRIDE = 16384 + BN * 128;           // A 16KB + B BN*128B
  __shared__ char lds[2 * (16384 + NF * 32 * 128)];
  const int tid  = threadIdx.x;
  const int lane = tid & 63;
  const int wid  = tid >> 6;
  const int wm = wid >> 1, wn = wid & 1;
  const int row0 = bx * 128;
  const int col0 = by * BN;
  const int l15 = lane & 15;
  const int l4  = lane >> 4;

  f32x4 acc[4][NF];
  const f32x4 zero4 = {0.f, 0.f, 0.f, 0.f};
#pragma unroll
  for (int m = 0; m < 4; ++m)
#pragma unroll
    for (int n = 0; n < NF; ++n) acc[m][n] = zero4;

  int aoff[2][4], boff[2][NF];
#pragma unroll
  for (int ks = 0; ks < 2; ++ks) {
#pragma unroll
    for (int m = 0; m < 4; ++m) {
      int ra = wm * 64 + m * 16 + l15;
      aoff[ks][m] = ra * 128 + (((ks * 4 + l4) ^ (ra & 7)) * 16);
    }
#pragma unroll
    for (int n = 0; n < NF; ++n) {
      int rb = wn * (NF * 16) + n * 16 + l15;
      boff[ks][n] = 16384 + rb * 128 + (((ks * 4 + l4) ^ (rb & 7)) * 16);
    }
  }

  const int NC = NF > 4 ? NF : 4;
  int rr[NC], cbp[NC];
#pragma unroll
  for (int c = 0; c < NC; ++c) {
    rr[c]  = c * 32 + (tid >> 3);
    cbp[c] = ((tid & 7) ^ (rr[c] & 7)) * 8;
  }
  const size_t abase = (size_t)row0 * K;
  const size_t wbase = (size_t)col0 * K;

  auto STAGE = [&](int buf, int kt) {
    char* bA = lds + buf * STRIDE + wid * 1024;
    char* bB = lds + buf * STRIDE + 16384 + wid * 1024;
#pragma unroll
    for (int c = 0; c < 4; ++c)
      async16(bA + c * 4096, A + abase + (size_t)rr[c] * K + kt + cbp[c]);
#pragma unroll
    for (int c = 0; c < NF; ++c)
      async16(bB + c * 4096, W + wbase + (size_t)rr[c] * K + kt + cbp[c]);
  };
  auto COMPUTE = [&](int buf) {
    const char* base = lds + buf * STRIDE;
#pragma unroll
    for (int ks = 0; ks < 2; ++ks) {
      bf16x8 af[4], bfr[NF];
#pragma unroll
      for (int m = 0; m < 4; ++m)  af[m]  = *(const bf16x8*)(base + aoff[ks][m]);
#pragma unroll
      for (int n = 0; n < NF; ++n) bfr[n] = *(const bf16x8*)(base + boff[ks][n]);
      __builtin_amdgcn_s_setprio(1);
#pragma unroll
      for (int m = 0; m < 4; ++m)
#pragma unroll
        for (int n = 0; n < NF; ++n)
          acc[m][n] = __builtin_amdgcn_mfma_f32_16x16x32_bf16(
              af[m], bfr[n], acc[m][n], 0, 0, 0);
      __builtin_amdgcn_s_setprio(0);
    }
  };

  STAGE(0, 0);
  __syncthreads();
  int cur = 0;
  for (int kt = 64; kt < K; kt += 64) {
    STAGE(cur ^ 1, kt);      // next-tile loads in flight during compute
    COMPUTE(cur);
    __syncthreads();         // drains vmcnt+lgkmcnt: next tile ready
    cur ^= 1;
  }
  COMPUTE(cur);

  float bcol[NF];
#pragma unroll
  for (int n = 0; n < NF; ++n)
    bcol[n] = (MODE == 0) ? 0.f : bias[col0 + wn * (NF * 16) + n * 16 + l15];

#pragma unroll
  for (int m = 0; m < 4; ++m) {
    int r0 = row0 + wm * 64 + m * 16 + l4 * 4;
#pragma unroll
    for (int n = 0; n < NF; ++n) {
      int c = col0 + wn * (NF * 16) + n * 16 + l15;
#pragma unroll
      for (int j = 0; j < 4; ++j) {
        size_t idx = (size_t)(r0 + j) * N + c;
        float v = acc[m][n][j];
        if (MODE == 0) {
          ((u16*)Out)[idx] = f2bf(v);
        } else if (MODE == 1) {
          ((u16*)Out)[idx] = f2bf(v + bcol[n]);
        } else if (MODE == 2) {
          ((u16*)Out)[idx] = f2bf(fmaxf(v + bcol[n], 0.f));
        } else {
          ((float*)Out)[idx] = fmaxf(v + bcol[n], 0.f);
        }
      }
    }
  }
}

__device__ __forceinline__ void cast_range(
    const float* s, u16* d, int n4, int idx0, int stride)
{
  for (int j = idx0; j < n4; j += stride) {
    float4 v = ((const float4*)s)[j];
    ushort4 o;
    o.x = f2bf(v.x); o.y = f2bf(v.y); o.z = f2bf(v.z); o.w = f2bf(v.w);
    ((ushort4*)d)[j] = o;
  }
}

// ---------------------------------------------------------------------------
// fuse + bias + casts, merged. Blocks:
//   [0,144)    : weight-fuse GEMM (NF=2, 6x12x2 tiles)  [needs prep output]
//   [144,528)  : bias-fuse (2 x 768 rows)               [reads raw inputs]
//   [528,1536) : cast query/ref/W1/W2 f32->bf16         [reads raw inputs]
// The BW/bias work hides the latency-bound GEMM.
// ---------------------------------------------------------------------------
__global__ __launch_bounds__(256) void k_fuse_cast(
    const u16* WoSaB, const u16* WvTSaB, u16* WsaF,
    const u16* WoCaB, const u16* WvTCaB, u16* WcaF,
    const float* WoSa, const float* bvSa, const float* boSa, float* bsaF,
    const float* WoCa, const float* bvCa, const float* boCa, float* bcaF,
    const float* query, u16* qf_bf, const float* ref, u16* rf_bf,
    const float* w1, u16* W1b, const float* w2, u16* W2b, int M)
{
  const int b = blockIdx.x;
  const int tid = threadIdx.x;
  if (b < 144) {
    int z = b / 72, r = b % 72;
    int bx = r % 6, by = r / 6;       // by 0..11 (NF=2: BN=64)
    gemm_body<0, 2>(z ? WoCaB : WoSaB, z ? WvTCaB : WvTSaB, nullptr,
                    z ? WcaF : WsaF, bx, by, DD, DD);
    return;
  }
  if (b < 528) {                      // bias: out[n] = dot(Wo[n,:], bv) + bo[n]
    int bb = b - 144;
    const float *Wo, *bv, *bo; float* out;
    if (bb < 192) { Wo = WoSa; bv = bvSa; bo = boSa; out = bsaF; }
    else          { Wo = WoCa; bv = bvCa; bo = boCa; out = bcaF; bb -= 192; }
    int lane = tid & 63;
    int n = bb * 4 + (tid >> 6);
    float s = 0.f;
    for (int k = lane; k < DD; k += 64) s += Wo[(size_t)n * DD + k] * bv[k];
#pragma unroll
    for (int o = 32; o > 0; o >>= 1) s += __shfl_down(s, o, 64);
    if (lane == 0) out[n] = s + bo[n];
    return;
  }
  const int nf4 = M * DD / 4;
  const int nw4 = DD * DD / 4;
  const int nw24 = 512 * DD / 4;
  const int i0 = (b - 528) * 256 + tid;
  const int str = (1536 - 528) * 256;
  cast_range(query, qf_bf, nf4, i0, str);
  cast_range(ref,   rf_bf, nf4, i0, str);
  cast_range(w1,    W1b,   nw4, i0, str);
  cast_range(w2,    W2b,   nw24, i0, str);
}

// att: 1-D grid 1024, XCD-chunked; residual handled in ln.
__global__ __launch_bounds__(256) void k_gemm_att(
    const u16* qfb, const u16* rfb, const u16* WsaF, const u16* WcaF,
    const float* bsa, const float* bca,
    u16* t1, u16* ca, int M)
{
  int bid = blockIdx.x;
  int xcd = bid & 7;
  int idx = bid >> 3;                 // 0..127
  int bx  = xcd * 8 + (idx & 7);
  int t   = idx >> 3;                 // 0..15
  int by  = t & 7;                    // 0..7
  int z   = t >> 3;                   // 0..1
  gemm_body<1, 3>(z ? rfb : qfb, z ? WcaF : WsaF, z ? bca : bsa,
                  z ? (void*)ca : (void*)t1, bx, by, DD, DD);
}

__global__ __launch_bounds__(256) void k_mlp1(
    const u16* xb, const u16* W1, const float* b1, u16* hb, int M)
{
  int bid = blockIdx.x;
  int xcd = bid & 7;
  int idx = bid >> 3;                 // 0..63
  int bx  = xcd * 8 + (idx & 7);
  int by  = idx >> 3;                 // 0..7
  gemm_body<2, 3>(xb, W1, b1, hb, bx, by, DD, DD);
}

__global__ __launch_bounds__(256) void k_mlp2(
    const u16* hb, const u16* W2, const float* b2, float* out, int M)
{
  int bid = blockIdx.x;
  int xcd = bid & 7;
  int idx = bid >> 3;                 // 0..63
  int bx  = xcd * 8 + (idx & 7);
  int by  = idx >> 3;                 // 0..7
  gemm_body<3, 2>(hb, W2, b2, out, bx, by, 512, DD);
}

// ---------------------------------------------------------------------------
// Prep (minimal dependency set for the fuse GEMM): [0,1152) transpose-cast
// Wv; [1152,...) cast WoSa/WoCa (~14 MB total).
// ---------------------------------------------------------------------------
__global__ __launch_bounds__(256) void k_prep(
    const float* sa_w_v, u16* WvTSaB, const float* ca_w_v, u16* WvTCaB,
    const float* s0, u16* d0, int n0, const float* s1, u16* d1, int n1)
{
  __shared__ float t[32][33];
  const int b = blockIdx.x;
  const int tid = threadIdx.x;

  if (b < 1152) {
    int z = b / 576, r = b % 576;
    const float* src = z ? ca_w_v : sa_w_v;
    u16* dst = z ? WvTCaB : WvTSaB;
    int by = (r / 24) * 32, bx = (r % 24) * 32;
    int x = tid & 31, y4 = tid >> 5;
#pragma unroll
    for (int i = 0; i < 32; i += 8)
      t[y4 + i][x] = src[(size_t)(by + y4 + i) * DD + bx + x];
    __syncthreads();
#pragma unroll
    for (int i = 0; i < 32; i += 8)
      dst[(size_t)(bx + y4 + i) * DD + by + x] = f2bf(t[x][y4 + i]);
    return;
  }
  int total = n0 + n1;
  int nblk = gridDim.x - 1152;
  for (int i = (b - 1152) * 256 + tid; i < total; i += nblk * 256) {
    int j = i; const float* s; u16* d;
    if (j < n0) { s = s0; d = d0; }
    else        { j -= n0; s = s1; d = d1; }
    float4 v = ((const float4*)s)[j];
    ushort4 o;
    o.x = f2bf(v.x); o.y = f2bf(v.y); o.z = f2bf(v.z); o.w = f2bf(v.w);
    ((ushort4*)d)[j] = o;
  }
}

// ---------------------------------------------------------------------------
// Double LayerNorm with residual: q = LN1(qf + t1); y = q + ca;
// x = relu(LN2(y)) -> bf16.
// ---------------------------------------------------------------------------
__global__ __launch_bounds__(256) void k_ln(
    const u16* __restrict__ t1, const u16* __restrict__ caB,
    const u16* __restrict__ resid,
    const float* __restrict__ g1, const float* __restrict__ b1,
    const float* __restrict__ g2, const float* __restrict__ b2,
    u16* __restrict__ xout, int M)
{
  int row = blockIdx.x * 4 + (threadIdx.x >> 6);
  int lane = threadIdx.x & 63;
  const ushort4* p1 = (const ushort4*)(t1 + (size_t)row * DD);
  const ushort4* pc = (const ushort4*)(caB + (size_t)row * DD);
  const ushort4* pr = (const ushort4*)(resid + (size_t)row * DD);
  const float4* pg1 = (const float4*)g1; const float4* pb1 = (const float4*)b1;
  const float4* pg2 = (const float4*)g2; const float4* pb2 = (const float4*)b2;

  float v[12];
  float s = 0.f, s2 = 0.f;
#pragma unroll
  for (int i = 0; i < 3; ++i) {
    ushort4 q = p1[lane + 64 * i];
    ushort4 rq = pr[lane + 64 * i];
    float a0 = bf2f(q.x) + bf2f(rq.x), a1 = bf2f(q.y) + bf2f(rq.y);
    float a2 = bf2f(q.z) + bf2f(rq.z), a3 = bf2f(q.w) + bf2f(rq.w);
    v[i*4+0] = a0; v[i*4+1] = a1; v[i*4+2] = a2; v[i*4+3] = a3;
    s  += a0 + a1 + a2 + a3;
    s2 += a0*a0 + a1*a1 + a2*a2 + a3*a3;
  }
#pragma unroll
  for (int o = 32; o > 0; o >>= 1) { s += __shfl_xor(s, o, 64); s2 += __shfl_xor(s2, o, 64); }
  float mu = s * (1.f / DD);
  float rs = rsqrtf(s2 * (1.f / DD) - mu * mu + LN_EPS);

  float y[12];
  s = 0.f; s2 = 0.f;
#pragma unroll
  for (int i = 0; i < 3; ++i) {
    float4 gg = pg1[lane + 64 * i]; float4 bb = pb1[lane + 64 * i];
    ushort4 cc = pc[lane + 64 * i];
    float y0 = (v[i*4+0] - mu) * rs * gg.x + bb.x + bf2f(cc.x);
    float y1 = (v[i*4+1] - mu) * rs * gg.y + bb.y + bf2f(cc.y);
    float y2 = (v[i*4+2] - mu) * rs * gg.z + bb.z + bf2f(cc.z);
    float y3 = (v[i*4+3] - mu) * rs * gg.w + bb.w + bf2f(cc.w);
    y[i*4+0] = y0; y[i*4+1] = y1; y[i*4+2] = y2; y[i*4+3] = y3;
    s  += y0 + y1 + y2 + y3;
    s2 += y0*y0 + y1*y1 + y2*y2 + y3*y3;
  }
#pragma unroll
  for (int o = 32; o > 0; o >>= 1) { s += __shfl_xor(s, o, 64); s2 += __shfl_xor(s2, o, 64); }
  float mu2 = s * (1.f / DD);
  float rs2 = rsqrtf(s2 * (1.f / DD) - mu2 * mu2 + LN_EPS);

  ushort4* po = (ushort4*)(xout + (size_t)row * DD);
#pragma unroll
  for (int i = 0; i < 3; ++i) {
    float4 gg = pg2[lane + 64 * i]; float4 bb = pb2[lane + 64 * i];
    ushort4 o;
    o.x = f2bf(fmaxf((y[i*4+0] - mu2) * rs2 * gg.x + bb.x, 0.f));
    o.y = f2bf(fmaxf((y[i*4+1] - mu2) * rs2 * gg.y + bb.y, 0.f));
    o.z = f2bf(fmaxf((y[i*4+2] - mu2) * rs2 * gg.z + bb.z, 0.f));
    o.w = f2bf(fmaxf((y[i*4+3] - mu2) * rs2 * gg.w + bb.w, 0.f));
    po[lane + 64 * i] = o;
  }
}

// ---------------------------------------------------------------------------
extern "C" void kernel_launch(void* const* d_in, const int* in_sizes, int n_in,
                              void* d_out, int out_size, void* d_ws, size_t ws_size,
                              hipStream_t stream) {
  const float* query    = (const float*)d_in[0];
  const float* ref      = (const float*)d_in[1];
  const float* sa_w_in  = (const float*)d_in[2];
  const float* sa_b_in  = (const float*)d_in[3];
  const float* sa_w_out = (const float*)d_in[4];
  const float* sa_b_out = (const float*)d_in[5];
  const float* ln1_g    = (const float*)d_in[6];
  const float* ln1_b    = (const float*)d_in[7];
  const float* ca_w_in  = (const float*)d_in[8];
  const float* ca_b_in  = (const float*)d_in[9];
  const float* ca_w_out = (const float*)d_in[10];
  const float* ca_b_out = (const float*)d_in[11];
  const float* ln2_g    = (const float*)d_in[12];
  const float* ln2_b    = (const float*)d_in[13];
  const float* w1       = (const float*)d_in[14];
  const float* b1       = (const float*)d_in[15];
  const float* w2       = (const float*)d_in[16];
  const float* b2       = (const float*)d_in[17];
  const int M = in_sizes[0] / DD;   // 8192

  char* p = (char*)d_ws;
  u16* qf_bf = (u16*)p; p += (size_t)M * DD * 2;   // residual input for ln
  u16* rf_bf = (u16*)p; p += (size_t)M * DD * 2;   // reused as ln output x
  u16* t1    = (u16*)p; p += (size_t)M * DD * 2;   // reused as h after ln
  u16* ca    = (u16*)p; p += (size_t)M * DD * 2;
  u16* WoSaB  = (u16*)p; p += DD * DD * 2;
  u16* WoCaB  = (u16*)p; p += DD * DD * 2;
  u16* WvTSaB = (u16*)p; p += DD * DD * 2;
  u16* WvTCaB = (u16*)p; p += DD * DD * 2;
  u16* W1b    = (u16*)p; p += DD * DD * 2;
  u16* W2b    = (u16*)p; p += 512 * DD * 2;
  u16* WsaF   = (u16*)p; p += DD * DD * 2;
  u16* WcaF   = (u16*)p; p += DD * DD * 2;
  float* bsaF = (float*)p; p += DD * 4;
  float* bcaF = (float*)p; p += DD * 4;

  const int nw = DD * DD / 4;

  k_prep<<<dim3(1152 + 384), 256, 0, stream>>>(
      sa_w_in + 2 * DD * DD, WvTSaB, ca_w_in + 2 * DD * DD, WvTCaB,
      sa_w_out, WoSaB, nw, ca_w_out, WoCaB, nw);

  k_fuse_cast<<<dim3(1536), 256, 0, stream>>>(
      WoSaB, WvTSaB, WsaF, WoCaB, WvTCaB, WcaF,
      sa_w_out, sa_b_in + 2 * DD, sa_b_out, bsaF,
      ca_w_out, ca_b_in + 2 * DD, ca_b_out, bcaF,
      query, qf_bf, ref, rf_bf,
      w1, W1b, w2, W2b, M);

  k_gemm_att<<<dim3(1024), 256, 0, stream>>>(
      qf_bf, rf_bf, WsaF, WcaF, bsaF, bcaF, t1, ca, M);

  k_ln<<<dim3(M / 4), 256, 0, stream>>>(
      t1, ca, qf_bf, ln1_g, ln1_b, ln2_g, ln2_b, rf_bf, M);

  k_mlp1<<<dim3(512), 256, 0, stream>>>(rf_bf, W1b, b1, t1, M);

  k_mlp2<<<dim3(512), 256, 0, stream>>>(t1, W2b, b2, (float*)d_out, M);
}

// Round 18
// 84.379 us; speedup vs baseline: 1.0118x; 1.0118x over previous
//
#include <hip/hip_runtime.h>
#include <stdint.h>

typedef unsigned short u16;
typedef __bf16 bf16x8 __attribute__((ext_vector_type(8)));
typedef float f32x4 __attribute__((ext_vector_type(4)));

#define DD 768
#define LN_EPS 1e-5f

__device__ __forceinline__ u16 f2bf(float f) {
  union { float f; unsigned u; } x; x.f = f;
  unsigned r = x.u + 0x7fffu + ((x.u >> 16) & 1u);
  return (u16)(r >> 16);
}
__device__ __forceinline__ float bf2f(u16 h) {
  union { unsigned u; float f; } x; x.u = ((unsigned)h) << 16; return x.f;
}

__device__ __forceinline__ void async16(void* ldsp, const void* g) {
  __builtin_amdgcn_global_load_lds(
      (const __attribute__((address_space(1))) void*)g,
      (__attribute__((address_space(3))) void*)ldsp,
      16, 0, 0);
}

// ---------------------------------------------------------------------------
// 128 x (NF*32) 2-phase GEMM (proven structure). 256 thr = 4 waves (2Mx2N);
// BK=64, 12 K-tiles. Swizzle: 16B chunk ^= (row&7) on pre-swizzled global
// source + ds_read addr; LDS writes linear. Zero bank conflicts (measured).
// MODE 0: bf16 raw; 1: bf16 acc+bias; 2: bf16 relu; 3: f32 relu.
// ---------------------------------------------------------------------------
template<int MODE, int NF>
__device__ __forceinline__ void gemm_body(
    const u16* __restrict__ A, const u16* __restrict__ W,
    const float* __restrict__ bias,
    void* __restrict__ Out, int bx, int by, int N, int K)
{
  const int BN = NF * 32;
  const int STRIDE = 16384 + BN * 128;           // A 16KB + B BN*128B
  __shared__ char lds[2 * (16384 + NF * 32 * 128)];
  const int tid  = threadIdx.x;
  const int lane = tid & 63;
  const int wid  = tid >> 6;
  const int wm = wid >> 1, wn = wid & 1;
  const int row0 = bx * 128;
  const int col0 = by * BN;
  const int l15 = lane & 15;
  const int l4  = lane >> 4;

  f32x4 acc[4][NF];
  const f32x4 zero4 = {0.f, 0.f, 0.f, 0.f};
#pragma unroll
  for (int m = 0; m < 4; ++m)
#pragma unroll
    for (int n = 0; n < NF; ++n) acc[m][n] = zero4;

  int aoff[2][4], boff[2][NF];
#pragma unroll
  for (int ks = 0; ks < 2; ++ks) {
#pragma unroll
    for (int m = 0; m < 4; ++m) {
      int ra = wm * 64 + m * 16 + l15;
      aoff[ks][m] = ra * 128 + (((ks * 4 + l4) ^ (ra & 7)) * 16);
    }
#pragma unroll
    for (int n = 0; n < NF; ++n) {
      int rb = wn * (NF * 16) + n * 16 + l15;
      boff[ks][n] = 16384 + rb * 128 + (((ks * 4 + l4) ^ (rb & 7)) * 16);
    }
  }

  const int NC = NF > 4 ? NF : 4;
  int rr[NC], cbp[NC];
#pragma unroll
  for (int c = 0; c < NC; ++c) {
    rr[c]  = c * 32 + (tid >> 3);
    cbp[c] = ((tid & 7) ^ (rr[c] & 7)) * 8;
  }
  const size_t abase = (size_t)row0 * K;
  const size_t wbase = (size_t)col0 * K;

  auto STAGE = [&](int buf, int kt) {
    char* bA = lds + buf * STRIDE + wid * 1024;
    char* bB = lds + buf * STRIDE + 16384 + wid * 1024;
#pragma unroll
    for (int c = 0; c < 4; ++c)
      async16(bA + c * 4096, A + abase + (size_t)rr[c] * K + kt + cbp[c]);
#pragma unroll
    for (int c = 0; c < NF; ++c)
      async16(bB + c * 4096, W + wbase + (size_t)rr[c] * K + kt + cbp[c]);
  };
  auto COMPUTE = [&](int buf) {
    const char* base = lds + buf * STRIDE;
#pragma unroll
    for (int ks = 0; ks < 2; ++ks) {
      bf16x8 af[4], bfr[NF];
#pragma unroll
      for (int m = 0; m < 4; ++m)  af[m]  = *(const bf16x8*)(base + aoff[ks][m]);
#pragma unroll
      for (int n = 0; n < NF; ++n) bfr[n] = *(const bf16x8*)(base + boff[ks][n]);
      __builtin_amdgcn_s_setprio(1);
#pragma unroll
      for (int m = 0; m < 4; ++m)
#pragma unroll
        for (int n = 0; n < NF; ++n)
          acc[m][n] = __builtin_amdgcn_mfma_f32_16x16x32_bf16(
              af[m], bfr[n], acc[m][n], 0, 0, 0);
      __builtin_amdgcn_s_setprio(0);
    }
  };

  STAGE(0, 0);
  __syncthreads();
  int cur = 0;
  for (int kt = 64; kt < K; kt += 64) {
    STAGE(cur ^ 1, kt);      // next-tile loads in flight during compute
    COMPUTE(cur);
    __syncthreads();         // drains vmcnt+lgkmcnt: next tile ready
    cur ^= 1;
  }
  COMPUTE(cur);

  float bcol[NF];
#pragma unroll
  for (int n = 0; n < NF; ++n)
    bcol[n] = (MODE == 0) ? 0.f : bias[col0 + wn * (NF * 16) + n * 16 + l15];

#pragma unroll
  for (int m = 0; m < 4; ++m) {
    int r0 = row0 + wm * 64 + m * 16 + l4 * 4;
#pragma unroll
    for (int n = 0; n < NF; ++n) {
      int c = col0 + wn * (NF * 16) + n * 16 + l15;
#pragma unroll
      for (int j = 0; j < 4; ++j) {
        size_t idx = (size_t)(r0 + j) * N + c;
        float v = acc[m][n][j];
        if (MODE == 0) {
          ((u16*)Out)[idx] = f2bf(v);
        } else if (MODE == 1) {
          ((u16*)Out)[idx] = f2bf(v + bcol[n]);
        } else if (MODE == 2) {
          ((u16*)Out)[idx] = f2bf(fmaxf(v + bcol[n], 0.f));
        } else {
          ((float*)Out)[idx] = fmaxf(v + bcol[n], 0.f);
        }
      }
    }
  }
}

__device__ __forceinline__ void cast_range(
    const float* s, u16* d, int n4, int idx0, int stride)
{
  for (int j = idx0; j < n4; j += stride) {
    float4 v = ((const float4*)s)[j];
    ushort4 o;
    o.x = f2bf(v.x); o.y = f2bf(v.y); o.z = f2bf(v.z); o.w = f2bf(v.w);
    ((ushort4*)d)[j] = o;
  }
}

// ---------------------------------------------------------------------------
// fuse + query/ref cast, merged: blocks [0,144) run the weight-fuse GEMM
// (NF=2, 6x12x2 tiles); blocks [144,1536) cast query/ref f32->bf16
// concurrently (75 MB of BW work hides the latency-bound GEMM).
// ---------------------------------------------------------------------------
__global__ __launch_bounds__(256) void k_fuse_cast(
    const u16* WoSaB, const u16* WvTSaB, u16* WsaF,
    const u16* WoCaB, const u16* WvTCaB, u16* WcaF,
    const float* query, u16* qf_bf, const float* ref, u16* rf_bf, int M)
{
  const int b = blockIdx.x;
  if (b < 144) {
    int z = b / 72, r = b % 72;
    int bx = r % 6, by = r / 6;       // by 0..11 (NF=2: BN=64, 768/64=12)
    gemm_body<0, 2>(z ? WoCaB : WoSaB, z ? WvTCaB : WvTSaB, nullptr,
                    z ? WcaF : WsaF, bx, by, DD, DD);
    return;
  }
  const int nf4 = M * DD / 4;
  const int i0 = (b - 144) * 256 + threadIdx.x;
  const int str = (1536 - 144) * 256;
  cast_range(query, qf_bf, nf4, i0, str);
  cast_range(ref,   rf_bf, nf4, i0, str);
}

// att: 1-D grid 1024, XCD-chunked; residual handled in ln.
__global__ __launch_bounds__(256) void k_gemm_att(
    const u16* qfb, const u16* rfb, const u16* WsaF, const u16* WcaF,
    const float* bsa, const float* bca,
    u16* t1, u16* ca, int M)
{
  int bid = blockIdx.x;
  int xcd = bid & 7;
  int idx = bid >> 3;                 // 0..127
  int bx  = xcd * 8 + (idx & 7);
  int t   = idx >> 3;                 // 0..15
  int by  = t & 7;                    // 0..7
  int z   = t >> 3;                   // 0..1
  gemm_body<1, 3>(z ? rfb : qfb, z ? WcaF : WsaF, z ? bca : bsa,
                  z ? (void*)ca : (void*)t1, bx, by, DD, DD);
}

__global__ __launch_bounds__(256) void k_mlp1(
    const u16* xb, const u16* W1, const float* b1, u16* hb, int M)
{
  int bid = blockIdx.x;
  int xcd = bid & 7;
  int idx = bid >> 3;                 // 0..63
  int bx  = xcd * 8 + (idx & 7);
  int by  = idx >> 3;                 // 0..7
  gemm_body<2, 3>(xb, W1, b1, hb, bx, by, DD, DD);
}

__global__ __launch_bounds__(256) void k_mlp2(
    const u16* hb, const u16* W2, const float* b2, float* out, int M)
{
  int bid = blockIdx.x;
  int xcd = bid & 7;
  int idx = bid >> 3;                 // 0..63
  int bx  = xcd * 8 + (idx & 7);
  int by  = idx >> 3;                 // 0..7
  gemm_body<3, 2>(hb, W2, b2, out, bx, by, 512, DD);
}

// ---------------------------------------------------------------------------
// Prep (weights only): [0,1152) transpose-cast Wv; [1152,1536) fused bias;
// [1536,...) cast Wo x2, W1, W2 (~19 MB total).
// ---------------------------------------------------------------------------
__global__ __launch_bounds__(256) void k_prep(
    const float* sa_w_v, u16* WvTSaB, const float* ca_w_v, u16* WvTCaB,
    const float* WoSa, const float* bvSa, const float* boSa, float* bsaF,
    const float* WoCa, const float* bvCa, const float* boCa, float* bcaF,
    const float* s0, u16* d0, int n0, const float* s1, u16* d1, int n1,
    const float* s2, u16* d2, int n2, const float* s3, u16* d3, int n3)
{
  __shared__ float t[32][33];
  const int b = blockIdx.x;
  const int tid = threadIdx.x;

  if (b < 1152) {
    int z = b / 576, r = b % 576;
    const float* src = z ? ca_w_v : sa_w_v;
    u16* dst = z ? WvTCaB : WvTSaB;
    int by = (r / 24) * 32, bx = (r % 24) * 32;
    int x = tid & 31, y4 = tid >> 5;
#pragma unroll
    for (int i = 0; i < 32; i += 8)
      t[y4 + i][x] = src[(size_t)(by + y4 + i) * DD + bx + x];
    __syncthreads();
#pragma unroll
    for (int i = 0; i < 32; i += 8)
      dst[(size_t)(bx + y4 + i) * DD + by + x] = f2bf(t[x][y4 + i]);
    return;
  }
  if (b < 1536) {
    int bb = b - 1152;
    const float *Wo, *bv, *bo; float* out;
    if (bb < 192) { Wo = WoSa; bv = bvSa; bo = boSa; out = bsaF; }
    else          { Wo = WoCa; bv = bvCa; bo = boCa; out = bcaF; bb -= 192; }
    int lane = tid & 63;
    int n = bb * 4 + (tid >> 6);
    float s = 0.f;
    for (int k = lane; k < DD; k += 64) s += Wo[(size_t)n * DD + k] * bv[k];
#pragma unroll
    for (int o = 32; o > 0; o >>= 1) s += __shfl_down(s, o, 64);
    if (lane == 0) out[n] = s + bo[n];
    return;
  }
  int total = n0 + n1 + n2 + n3;
  int nblk = gridDim.x - 1536;
  for (int i = (b - 1536) * 256 + tid; i < total; i += nblk * 256) {
    int j = i; const float* s; u16* d;
    if (j < n0) { s = s0; d = d0; }
    else { j -= n0;
      if (j < n1) { s = s1; d = d1; }
      else { j -= n1;
        if (j < n2) { s = s2; d = d2; }
        else { j -= n2; s = s3; d = d3; }
      }
    }
    float4 v = ((const float4*)s)[j];
    ushort4 o;
    o.x = f2bf(v.x); o.y = f2bf(v.y); o.z = f2bf(v.z); o.w = f2bf(v.w);
    ((ushort4*)d)[j] = o;
  }
}

// ---------------------------------------------------------------------------
// Double LayerNorm with residual: q = LN1(qf + t1); y = q + ca;
// x = relu(LN2(y)) -> bf16.
// ---------------------------------------------------------------------------
__global__ __launch_bounds__(256) void k_ln(
    const u16* __restrict__ t1, const u16* __restrict__ caB,
    const u16* __restrict__ resid,
    const float* __restrict__ g1, const float* __restrict__ b1,
    const float* __restrict__ g2, const float* __restrict__ b2,
    u16* __restrict__ xout, int M)
{
  int row = blockIdx.x * 4 + (threadIdx.x >> 6);
  int lane = threadIdx.x & 63;
  const ushort4* p1 = (const ushort4*)(t1 + (size_t)row * DD);
  const ushort4* pc = (const ushort4*)(caB + (size_t)row * DD);
  const ushort4* pr = (const ushort4*)(resid + (size_t)row * DD);
  const float4* pg1 = (const float4*)g1; const float4* pb1 = (const float4*)b1;
  const float4* pg2 = (const float4*)g2; const float4* pb2 = (const float4*)b2;

  float v[12];
  float s = 0.f, s2 = 0.f;
#pragma unroll
  for (int i = 0; i < 3; ++i) {
    ushort4 q = p1[lane + 64 * i];
    ushort4 rq = pr[lane + 64 * i];
    float a0 = bf2f(q.x) + bf2f(rq.x), a1 = bf2f(q.y) + bf2f(rq.y);
    float a2 = bf2f(q.z) + bf2f(rq.z), a3 = bf2f(q.w) + bf2f(rq.w);
    v[i*4+0] = a0; v[i*4+1] = a1; v[i*4+2] = a2; v[i*4+3] = a3;
    s  += a0 + a1 + a2 + a3;
    s2 += a0*a0 + a1*a1 + a2*a2 + a3*a3;
  }
#pragma unroll
  for (int o = 32; o > 0; o >>= 1) { s += __shfl_xor(s, o, 64); s2 += __shfl_xor(s2, o, 64); }
  float mu = s * (1.f / DD);
  float rs = rsqrtf(s2 * (1.f / DD) - mu * mu + LN_EPS);

  float y[12];
  s = 0.f; s2 = 0.f;
#pragma unroll
  for (int i = 0; i < 3; ++i) {
    float4 gg = pg1[lane + 64 * i]; float4 bb = pb1[lane + 64 * i];
    ushort4 cc = pc[lane + 64 * i];
    float y0 = (v[i*4+0] - mu) * rs * gg.x + bb.x + bf2f(cc.x);
    float y1 = (v[i*4+1] - mu) * rs * gg.y + bb.y + bf2f(cc.y);
    float y2 = (v[i*4+2] - mu) * rs * gg.z + bb.z + bf2f(cc.z);
    float y3 = (v[i*4+3] - mu) * rs * gg.w + bb.w + bf2f(cc.w);
    y[i*4+0] = y0; y[i*4+1] = y1; y[i*4+2] = y2; y[i*4+3] = y3;
    s  += y0 + y1 + y2 + y3;
    s2 += y0*y0 + y1*y1 + y2*y2 + y3*y3;
  }
#pragma unroll
  for (int o = 32; o > 0; o >>= 1) { s += __shfl_xor(s, o, 64); s2 += __shfl_xor(s2, o, 64); }
  float mu2 = s * (1.f / DD);
  float rs2 = rsqrtf(s2 * (1.f / DD) - mu2 * mu2 + LN_EPS);

  ushort4* po = (ushort4*)(xout + (size_t)row * DD);
#pragma unroll
  for (int i = 0; i < 3; ++i) {
    float4 gg = pg2[lane + 64 * i]; float4 bb = pb2[lane + 64 * i];
    ushort4 o;
    o.x = f2bf(fmaxf((y[i*4+0] - mu2) * rs2 * gg.x + bb.x, 0.f));
    o.y = f2bf(fmaxf((y[i*4+1] - mu2) * rs2 * gg.y + bb.y, 0.f));
    o.z = f2bf(fmaxf((y[i*4+2] - mu2) * rs2 * gg.z + bb.z, 0.f));
    o.w = f2bf(fmaxf((y[i*4+3] - mu2) * rs2 * gg.w + bb.w, 0.f));
    po[lane + 64 * i] = o;
  }
}

// ---------------------------------------------------------------------------
extern "C" void kernel_launch(void* const* d_in, const int* in_sizes, int n_in,
                              void* d_out, int out_size, void* d_ws, size_t ws_size,
                              hipStream_t stream) {
  const float* query    = (const float*)d_in[0];
  const float* ref      = (const float*)d_in[1];
  const float* sa_w_in  = (const float*)d_in[2];
  const float* sa_b_in  = (const float*)d_in[3];
  const float* sa_w_out = (const float*)d_in[4];
  const float* sa_b_out = (const float*)d_in[5];
  const float* ln1_g    = (const float*)d_in[6];
  const float* ln1_b    = (const float*)d_in[7];
  const float* ca_w_in  = (const float*)d_in[8];
  const float* ca_b_in  = (const float*)d_in[9];
  const float* ca_w_out = (const float*)d_in[10];
  const float* ca_b_out = (const float*)d_in[11];
  const float* ln2_g    = (const float*)d_in[12];
  const float* ln2_b    = (const float*)d_in[13];
  const float* w1       = (const float*)d_in[14];
  const float* b1       = (const float*)d_in[15];
  const float* w2       = (const float*)d_in[16];
  const float* b2       = (const float*)d_in[17];
  const int M = in_sizes[0] / DD;   // 8192

  char* p = (char*)d_ws;
  u16* qf_bf = (u16*)p; p += (size_t)M * DD * 2;   // residual input for ln
  u16* rf_bf = (u16*)p; p += (size_t)M * DD * 2;   // reused as ln output x
  u16* t1    = (u16*)p; p += (size_t)M * DD * 2;   // reused as h after ln
  u16* ca    = (u16*)p; p += (size_t)M * DD * 2;
  u16* WoSaB  = (u16*)p; p += DD * DD * 2;
  u16* WoCaB  = (u16*)p; p += DD * DD * 2;
  u16* WvTSaB = (u16*)p; p += DD * DD * 2;
  u16* WvTCaB = (u16*)p; p += DD * DD * 2;
  u16* W1b    = (u16*)p; p += DD * DD * 2;
  u16* W2b    = (u16*)p; p += 512 * DD * 2;
  u16* WsaF   = (u16*)p; p += DD * DD * 2;
  u16* WcaF   = (u16*)p; p += DD * DD * 2;
  float* bsaF = (float*)p; p += DD * 4;
  float* bcaF = (float*)p; p += DD * 4;

  const int nw  = DD * DD / 4;
  const int nw2 = 512 * DD / 4;

  k_prep<<<dim3(1536 + 768), 256, 0, stream>>>(
      sa_w_in + 2 * DD * DD, WvTSaB, ca_w_in + 2 * DD * DD, WvTCaB,
      sa_w_out, sa_b_in + 2 * DD, sa_b_out, bsaF,
      ca_w_out, ca_b_in + 2 * DD, ca_b_out, bcaF,
      sa_w_out, WoSaB, nw, ca_w_out, WoCaB, nw,
      w1, W1b, nw, w2, W2b, nw2);

  k_fuse_cast<<<dim3(1536), 256, 0, stream>>>(
      WoSaB, WvTSaB, WsaF, WoCaB, WvTCaB, WcaF,
      query, qf_bf, ref, rf_bf, M);

  k_gemm_att<<<dim3(1024), 256, 0, stream>>>(
      qf_bf, rf_bf, WsaF, WcaF, bsaF, bcaF, t1, ca, M);

  k_ln<<<dim3(M / 4), 256, 0, stream>>>(
      t1, ca, qf_bf, ln1_g, ln1_b, ln2_g, ln2_b, rf_bf, M);

  k_mlp1<<<dim3(512), 256, 0, stream>>>(rf_bf, W1b, b1, t1, M);

  k_mlp2<<<dim3(512), 256, 0, stream>>>(t1, W2b, b2, (float*)d_out, M);
}